// Round 1
// baseline (69.137 us; speedup 1.0000x reference)
//
#include <hip/hip_runtime.h>
#include <math.h>

// Problem constants (fixed by setup_inputs)
constexpr int B       = 2;
constexpr int N       = 32768;
constexpr int D       = 3;
constexpr int M_FULL  = 8192;
constexpr int SUBDIV  = 8;
constexpr int M       = M_FULL / SUBDIV;   // 1024 subsampled verts per (b,d)
constexpr int K       = 512;               // value buckets over [-4,4]
constexpr float LO    = -4.0f;
constexpr float INV_W = 64.0f;             // 1 / (8/512)
constexpr float K4    = 5.770780163555852f; // 4*log2(e): e^{4t} = 2^{K4*t}
constexpr int NPAIR   = B * D;             // 6 (b,d) pairs

// Query kernel geometry: whole grid co-resident (768 blocks * 4 waves = 3072
// waves on 256 CUs = 12 waves/CU; LDS 18.3KB -> up to 8 blocks/CU).
constexpr int QBLOCK  = 256;
constexpr int QCHUNKS = N / QBLOCK;        // 128
constexpr int QGRID   = NPAIR * QCHUNKS;   // 768

// Workspace layout (110.6 KB total):
//   aggG : NPAIR*K float4   @ 0       (49152 B)  (Ap[j], Sp[j], Am[j+1], Sm[j+1])
//   vwG  : NPAIR*M  float2  @ 49152   (49152 B)  bucket-grouped (v, w)
//   begG : NPAIR*(K+1) int  @ 98304   (12312 B)  bucket fences, beg[K] = M
constexpr int OFF_VW  = 49152;
constexpr int OFF_BEG = 98304;

// ---- 512-element wave-parallel scans (one wave, lane owns 8 slots) ----
__device__ inline void scan512_pre(float* a) {   // exclusive prefix, small-first
    const int lane = threadIdx.x & 63;
    const int base = lane * 8;
    float xv[8], e[8]; float ls = 0.f;
    #pragma unroll
    for (int t = 0; t < 8; ++t) xv[t] = a[base + t];
    #pragma unroll
    for (int t = 0; t < 8; ++t) { e[t] = ls; ls += xv[t]; }
    float inc = ls;
    #pragma unroll
    for (int off = 1; off < 64; off <<= 1) {
        const float tmp = __shfl_up(inc, off, 64);
        if (lane >= off) inc += tmp;
    }
    const float exoff = inc - ls;
    #pragma unroll
    for (int t = 0; t < 8; ++t) a[base + t] = exoff + e[t];
}

__device__ inline void scan512_suf(float* a) {   // inclusive suffix, small-first
    const int lane = threadIdx.x & 63;
    const int base = lane * 8;
    float xv[8], e[8]; float ls = 0.f;
    #pragma unroll
    for (int t = 0; t < 8; ++t) xv[t] = a[base + t];
    #pragma unroll
    for (int t = 7; t >= 0; --t) { e[t] = ls; ls += xv[t]; }
    float inc = ls;
    #pragma unroll
    for (int off = 1; off < 64; off <<= 1) {
        const float tmp = __shfl_down(inc, off, 64);
        if (lane + off < 64) inc += tmp;
    }
    const float exoff = inc - ls;
    #pragma unroll
    for (int t = 0; t < 8; ++t) a[base + t] = exoff + e[t] + xv[t];
}

__device__ inline void scan512_i(const int* cntA, int* begA, int* curA) {
    const int lane = threadIdx.x & 63;
    const int base = lane * 8;
    int xv[8], e[8]; int ls = 0;
    #pragma unroll
    for (int t = 0; t < 8; ++t) xv[t] = cntA[base + t];
    #pragma unroll
    for (int t = 0; t < 8; ++t) { e[t] = ls; ls += xv[t]; }
    int inc = ls;
    #pragma unroll
    for (int off = 1; off < 64; off <<= 1) {
        const int tmp = __shfl_up(inc, off, 64);
        if (lane >= off) inc += tmp;
    }
    const int exoff = inc - ls;
    #pragma unroll
    for (int t = 0; t < 8; ++t) {
        begA[base + t] = exoff + e[t];
        curA[base + t] = exoff + e[t];
    }
}

// ---- Build: once per (b,d) pair. 6 blocks x 1024 threads. ----
__global__ __launch_bounds__(1024) void build_kernel(
    const float* __restrict__ dverts,
    const float* __restrict__ mverts,
    float4* __restrict__ aggG,
    float2* __restrict__ vwG,
    int*    __restrict__ begG)
{
    __shared__ float gAp[K], gSp[K], gAm[K], gSm[K];
    __shared__ int   cnt[K], beg[K], cur[K];

    const int tid = threadIdx.x;
    const int p = blockIdx.x;         // pair 0..5
    const int b = p / 3, d = p % 3;

    if (tid < K) {
        cnt[tid] = 0; gAp[tid] = 0.f; gSp[tid] = 0.f; gAm[tid] = 0.f; gSm[tid] = 0.f;
    }
    __syncthreads();

    const int g = (b * M_FULL + tid * SUBDIV) * D + d;
    const float v = dverts[g];
    const float w = mverts[g];
    const float epv = __builtin_amdgcn_exp2f( K4 * v);   // e^{4v}
    const float emv = __builtin_amdgcn_exp2f(-K4 * v);   // e^{-4v}
    int bj = (int)floorf((v - LO) * INV_W);
    bj = bj < 0 ? 0 : (bj > K - 1 ? K - 1 : bj);
    atomicAdd(&cnt[bj], 1);
    atomicAdd(&gAp[bj], w * epv);
    atomicAdd(&gSp[bj], epv);
    atomicAdd(&gAm[bj], w * emv);
    atomicAdd(&gSm[bj], emv);
    __syncthreads();

    const int wid = tid >> 6;
    if      (wid == 0) scan512_i(cnt, beg, cur);
    else if (wid == 1) scan512_pre(gAp);   // exclusive prefix (buckets < j)
    else if (wid == 2) scan512_pre(gSp);
    else if (wid == 3) scan512_suf(gAm);   // inclusive suffix (buckets >= j)
    else if (wid == 4) scan512_suf(gSm);
    __syncthreads();

    // Packed aggregates: one ds_read_b128 at query time.
    if (tid < K) {
        const float am = (tid < K - 1) ? gAm[tid + 1] : 0.f;
        const float sm = (tid < K - 1) ? gSm[tid + 1] : 0.f;
        aggG[p * K + tid] = make_float4(gAp[tid], gSp[tid], am, sm);
        begG[p * (K + 1) + tid] = beg[tid];
        if (tid == 0) begG[p * (K + 1) + K] = M;
    }
    // Counting scatter of (v,w) into bucket-grouped order.
    const int pos = atomicAdd(&cur[bj], 1);
    vwG[p * M + pos] = make_float2(v, w);
}

// ---- Query: one output element per thread. 768 blocks x 256 threads. ----
__global__ __launch_bounds__(QBLOCK) void query_kernel(
    const float* __restrict__ x,
    const float4* __restrict__ aggG,
    const float4* __restrict__ vwG4,   // vwG viewed as float4 for staging
    const int*    __restrict__ begG,
    float* __restrict__ out)
{
    __shared__ float4 agg[K];       // 8 KB
    __shared__ float2 vw[M];        // 8 KB
    __shared__ int    sbeg[K + 1];  // 2052 B

    const int tid = threadIdx.x;
    const int p = blockIdx.x >> 7;      // pair 0..5  (blockIdx / 128)
    const int c = blockIdx.x & 127;     // chunk within pair
    const int b = p / 3, d = p % 3;

    // Issue the x load early so its HBM latency overlaps the LDS staging.
    const int n = c * QBLOCK + tid;
    const int o = (b * N + n) * D + d;
    const float xq = x[o];

    // Stage structures (all coalesced dwordx4).
    agg[tid]        = aggG[p * K + tid];
    agg[tid + 256]  = aggG[p * K + tid + 256];
    float4* vwv = (float4*)vw;
    vwv[tid]        = vwG4[p * (M / 2) + tid];
    vwv[tid + 256]  = vwG4[p * (M / 2) + tid + 256];
    sbeg[tid]       = begG[p * (K + 1) + tid];
    sbeg[tid + 256] = begG[p * (K + 1) + tid + 256];
    if (tid == 0) sbeg[K] = begG[p * (K + 1) + K];
    __syncthreads();

    int j = (int)floorf((xq - LO) * INV_W);
    j = j < 0 ? 0 : (j > K - 1 ? K - 1 : j);

    const float en  = __builtin_amdgcn_exp2f(-K4 * xq);  // e^{-4x}
    const float epx = __builtin_amdgcn_exp2f( K4 * xq);  // e^{+4x}

    const float4 a = agg[j];            // (Ap, Sp, Am, Sm) in one b128
    const int s0 = sbeg[j], s1 = sbeg[j + 1];

    float rAp = 0.f, rSp = 0.f, rAm = 0.f, rSm = 0.f;
    for (int i = s0; i < s1; ++i) {
        const float2 pv = vw[i];        // one ds_read_b64 per residual
        const bool le = (pv.x <= xq);
        const float t  = __builtin_amdgcn_exp2f(le ? K4 * pv.x : -K4 * pv.x);
        const float wt = pv.y * t;
        rAp += le ? wt : 0.f;
        rSp += le ? t  : 0.f;
        rAm += le ? 0.f : wt;
        rSm += le ? 0.f : t;
    }
    out[o] = (en * (a.x + rAp) + epx * (a.z + rAm)) /
             (en * (a.y + rSp) + epx * (a.w + rSm));
}

extern "C" void kernel_launch(void* const* d_in, const int* in_sizes, int n_in,
                              void* d_out, int out_size, void* d_ws, size_t ws_size,
                              hipStream_t stream) {
    const float* x  = (const float*)d_in[0];
    const float* dv = (const float*)d_in[1];
    const float* mv = (const float*)d_in[2];
    float* out = (float*)d_out;

    char* ws = (char*)d_ws;
    float4* aggG = (float4*)ws;
    float2* vwG  = (float2*)(ws + OFF_VW);
    int*    begG = (int*)(ws + OFF_BEG);

    build_kernel<<<NPAIR, 1024, 0, stream>>>(dv, mv, aggG, vwG, begG);
    query_kernel<<<QGRID, QBLOCK, 0, stream>>>(x, aggG, (const float4*)vwG, begG, out);
}